// Round 15
// baseline (142.489 us; speedup 1.0000x reference)
//
#include <hip/hip_runtime.h>
#include <hip/hip_bf16.h>

typedef unsigned short u16;
typedef __attribute__((ext_vector_type(8))) short bf16x8;
typedef __attribute__((ext_vector_type(4))) float f32x4;
typedef __attribute__((ext_vector_type(4))) unsigned int u32x4;

#define LOG2E 1.44269504088896340736f

static __device__ __forceinline__ float b2f(u16 u) {
    union { float f; unsigned int i; } v; v.i = ((unsigned int)u) << 16; return v.f;
}
static __device__ __forceinline__ u16 f2b(float f) {
    unsigned int x = __builtin_bit_cast(unsigned int, f);
    unsigned int r = (x + 0x7fffu + ((x >> 16) & 1u)) >> 16;
    return (u16)r;
}
static __device__ __forceinline__ void gll16(const u16* g, u16* l) {
    __builtin_amdgcn_global_load_lds((const __attribute__((address_space(1))) void*)g,
                                     (__attribute__((address_space(3))) void*)l, 16, 0, 0);
}
static __device__ __forceinline__ float fexp2(float x) {
    float r; asm("v_exp_f32 %0, %1" : "=v"(r) : "v"(x)); return r;
}

// ---------------- fused fp32 -> bf16 convert ----------------
__global__ __launch_bounds__(256) void cvt_all(const float* __restrict__ x,
                                               const float* __restrict__ w0, const float* __restrict__ w1,
                                               const float* __restrict__ w2, const float* __restrict__ w3,
                                               const float* __restrict__ w4, u16* __restrict__ dst) {
    size_t c = (size_t)blockIdx.x * 256 + threadIdx.x;
    size_t e = c * 4;
    const float* s; size_t off;
    const size_t M4 = (size_t)4 << 20, M1 = (size_t)1 << 20;
    if (e < M4) { s = x; off = e; }
    else {
        size_t r = e - M4; int wsel = (int)(r >> 20); off = r & (M1 - 1);
        s = wsel == 0 ? w0 : wsel == 1 ? w1 : wsel == 2 ? w2 : wsel == 3 ? w3 : w4;
    }
    float4 v = *(const float4*)(s + off);
    u16* d = dst + e;
    d[0] = f2b(v.x); d[1] = f2b(v.y); d[2] = f2b(v.z); d[3] = f2b(v.w);
}

// ---------------- GEMM body (R9 known-good structure), tm/tn passed in ----------------
template<int WM>
static __device__ __forceinline__ void gemm_body(const u16* __restrict__ A, const u16* __restrict__ W,
                                                 const float* __restrict__ bias, void* __restrict__ outp,
                                                 int mode, u16* Al, u16* Bl, int tm, int tn) {
    const int tid = threadIdx.x, lane = tid & 63, w = tid >> 6;
    const int wr = w >> 1, wc = w & 1;
    const int l15 = lane & 15, lhi = lane >> 4;

    f32x4 acc[WM][4] = {};

    for (int kt = 0; kt < 16; ++kt) {
        const int k0 = kt * 64;
        #pragma unroll
        for (int i = 0; i < WM; ++i) {
            int rl = i * 32 + w * 8 + (lane >> 3);
            int c  = (lane & 7) ^ (rl & 7);
            gll16(A + (size_t)(tm + rl) * 1024 + k0 + c * 8, Al + (i * 32 + w * 8) * 64);
        }
        #pragma unroll
        for (int i = 0; i < 4; ++i) {
            int rl = i * 32 + w * 8 + (lane >> 3);
            int c  = (lane & 7) ^ (rl & 7);
            gll16(W + (size_t)(tn + rl) * 1024 + k0 + c * 8, Bl + (i * 32 + w * 8) * 64);
        }
        __syncthreads();
        #pragma unroll
        for (int ks = 0; ks < 2; ++ks) {
            bf16x8 af[WM], bfr[4];
            #pragma unroll
            for (int mi = 0; mi < WM; ++mi) {
                int row = wr * (WM * 16) + mi * 16 + l15;
                int cc = (ks * 4 + lhi) ^ (row & 7);
                af[mi] = *(const bf16x8*)(Al + row * 64 + cc * 8);
            }
            #pragma unroll
            for (int ni = 0; ni < 4; ++ni) {
                int row = wc * 64 + ni * 16 + l15;
                int cc = (ks * 4 + lhi) ^ (row & 7);
                bfr[ni] = *(const bf16x8*)(Bl + row * 64 + cc * 8);
            }
            #pragma unroll
            for (int mi = 0; mi < WM; ++mi)
                #pragma unroll
                for (int ni = 0; ni < 4; ++ni)
                    acc[mi][ni] = __builtin_amdgcn_mfma_f32_16x16x32_bf16(af[mi], bfr[ni], acc[mi][ni], 0, 0, 0);
        }
        __syncthreads();
    }

    float bcol[4];
    #pragma unroll
    for (int ni = 0; ni < 4; ++ni) bcol[ni] = bias[tn + wc * 64 + ni * 16 + l15];

    #pragma unroll
    for (int mi = 0; mi < WM; ++mi)
        #pragma unroll
        for (int ni = 0; ni < 4; ++ni)
            #pragma unroll
            for (int r = 0; r < 4; ++r) {
                int rg = tm + wr * (WM * 16) + mi * 16 + lhi * 4 + r;
                int cg = tn + wc * 64 + ni * 16 + l15;
                float v = acc[mi][ni][r] + bcol[ni];
                if (mode == 2) {
                    ((float*)outp)[(size_t)rg * 1024 + cg] = v;
                } else {
                    int b = rg >> 11, t = rg & 2047, h = cg >> 6, d = cg & 63;
                    if (mode == 0)
                        ((u16*)outp)[(((size_t)(b * 16 + h)) * 2048 + t) * 128 + d] = f2b(v);
                    else
                        ((u16*)outp)[(((size_t)(b * 16 + h)) * 2048 + t) * 64 + d] = f2b(v);
                }
            }
}

struct ProjArgs {
    const u16* W[4];
    const float* b[4];
    u16* out[4];
};

// ---------------- projection GEMM + XCD-chunked dispatch remap (R11, verified) ----------------
__global__ __launch_bounds__(256) void gemm_proj(const u16* __restrict__ A, ProjArgs pa) {
    __shared__ u16 Al[128 * 64];
    __shared__ u16 Bl[128 * 64];
    const int d = blockIdx.x + 8 * blockIdx.y + 256 * blockIdx.z;
    const int c = d & 7, wtn = d >> 3;
    const int z = c >> 1, yh = c & 1;
    const int yy = yh * 16 + (wtn >> 3);
    const int xx = wtn & 7;
    gemm_body<4>(A, pa.W[z], pa.b[z], pa.out[z], (z < 2) ? 0 : 1, Al, Bl, yy * 128, xx * 128);
}

__global__ __launch_bounds__(256) void gemm_out2(const u16* __restrict__ A, const u16* __restrict__ W,
                                                 const float* __restrict__ bias, void* __restrict__ out) {
    __shared__ u16 Al[64 * 64];
    __shared__ u16 Bl[128 * 64];
    const int d = blockIdx.x + 8 * blockIdx.y;
    const int c = d & 7, wtn = d >> 3;
    const int yy = c * 8 + (wtn >> 3);
    const int xx = wtn & 7;
    gemm_body<2>(A, W, bias, out, 2, Al, Bl, yy * 64, xx * 128);
}

// ---------------- fused small kernels (R9, verified) ----------------
__global__ __launch_bounds__(256) void fuse_small(u16* __restrict__ Qa, const u16* __restrict__ Tp,
                                                  const u16* __restrict__ V, u16* __restrict__ VT,
                                                  u16* __restrict__ Ka) {
    __shared__ char shmem[64 * 72 * 2];
    const int b = blockIdx.x, tid = threadIdx.x;

    if (b < 2048) {
        int idx = b * 256 + tid;
        int tg = idx >> 3, dc = idx & 7;
        bf16x8 q = *(const bf16x8*)(Qa + (size_t)tg * 128 + dc * 8);
        bf16x8 tt = *(const bf16x8*)(Tp + (size_t)tg * 64 + dc * 8);
        bf16x8 o;
        #pragma unroll
        for (int j = 0; j < 8; ++j) o[j] = (short)f2b(b2f((u16)q[j]) * b2f((u16)tt[j]));
        *(bf16x8*)(Qa + (size_t)tg * 128 + 64 + dc * 8) = o;
    } else if (b < 3072) {
        u16 (*tile)[72] = (u16(*)[72])shmem;
        const int r0 = b - 2048;
        const int bh = r0 >> 5, tc = r0 & 31;
        const u16* Vh = V + ((size_t)bh * 2048 + tc * 64) * 64;
        u16* VTh = VT + (size_t)bh * 64 * 2048 + tc * 64;
        for (int i = 0; i < 2; ++i) {
            int f = i * 256 + tid;
            int r = f >> 3, dc = f & 7;
            bf16x8 v = *(const bf16x8*)(Vh + r * 64 + dc * 8);
            #pragma unroll
            for (int j = 0; j < 8; ++j) tile[dc * 8 + j][r] = (u16)v[j];
        }
        __syncthreads();
        for (int i = 0; i < 2; ++i) {
            int f = i * 256 + tid;
            int d = f >> 3, t8 = (f & 7) * 8;
            bf16x8 o;
            #pragma unroll
            for (int j = 0; j < 8; ++j) {
                int pos = t8 + j;
                int key = (pos & 32) + 16 * ((pos >> 2) & 1) + 4 * ((pos >> 3) & 3) + (pos & 3);
                o[j] = (short)tile[d][key];
            }
            *(bf16x8*)(VTh + (size_t)d * 2048 + t8) = o;
        }
    } else {
        float4* sums = (float4*)shmem;
        const int r0 = b - 3072;
        const int bh = r0 & 31, dg = r0 >> 5;
        u16* Kh = Ka + (size_t)bh * 2048 * 128;
        const u16* Vh = V + (size_t)bh * 2048 * 64;
        const int quad = tid & 3, c = tid >> 2;
        const int d0 = dg * 16 + quad * 4;
        float s0 = 0.f, s1 = 0.f, s2 = 0.f, s3 = 0.f;
        for (int i = 0; i < 32; ++i) {
            int t = c * 32 + i;
            ushort4 kv = *(const ushort4*)(Kh + (size_t)t * 128 + d0);
            ushort4 vv = *(const ushort4*)(Vh + (size_t)t * 64 + d0);
            s0 += b2f(kv.x) * b2f(vv.x);
            s1 += b2f(kv.y) * b2f(vv.y);
            s2 += b2f(kv.z) * b2f(vv.z);
            s3 += b2f(kv.w) * b2f(vv.w);
        }
        float4 sv; sv.x = s0; sv.y = s1; sv.z = s2; sv.w = s3;
        sums[c * 4 + quad] = sv;
        __syncthreads();
        float4 run; run.x = run.y = run.z = run.w = 0.f;
        for (int cc = 0; cc < c; ++cc) {
            float4 ss = sums[cc * 4 + quad];
            run.x += ss.x; run.y += ss.y; run.z += ss.z; run.w += ss.w;
        }
        for (int i = 0; i < 32; ++i) {
            int t = c * 32 + i;
            ushort4 kv = *(const ushort4*)(Kh + (size_t)t * 128 + d0);
            ushort4 vv = *(const ushort4*)(Vh + (size_t)t * 64 + d0);
            run.x += b2f(kv.x) * b2f(vv.x);
            run.y += b2f(kv.y) * b2f(vv.y);
            run.z += b2f(kv.z) * b2f(vv.z);
            run.w += b2f(kv.w) * b2f(vv.w);
            ushort4 o;
            o.x = f2b(run.x * 0.125f); o.y = f2b(run.y * 0.125f);
            o.z = f2b(run.z * 0.125f); o.w = f2b(run.w * 0.125f);
            *(ushort4*)(Kh + (size_t)t * 128 + 64 + d0) = o;
        }
    }
}

// ---------------- attnSK: attn5 structure, split-K over key halves -> 1024 blocks (3/CU) ----------------
// Max-free softmax makes halves combine by pure addition: O = (P0+P1)/(ls0+ls1).
// Partials stored UNNORMALIZED bf16 (Obuf layout); ls per (half, bh, q) f32.
__global__ __launch_bounds__(256, 3) void attnSK(const u16* __restrict__ Qa, const u16* __restrict__ Ka,
                                                 const u16* __restrict__ VT,
                                                 u16* __restrict__ P0g, u16* __restrict__ P1g,
                                                 float* __restrict__ Ls) {
    const int wg = blockIdx.x;                 // 1024
    const int xcd = wg & 7, slot = wg >> 3;    // 0..127
    const int bh = xcd * 4 + (slot >> 5);
    const int sub = slot & 31;
    const int qp = sub & 15, half = sub >> 4;
    const int tiL = qp, tiH = 31 - qp;
    const int q0L = tiL * 64, q0H = tiH * 64;
    const int NT = tiH + 1;                    // 17..32
    const int mid = NT >> 1;
    const int lo = half ? mid : 0;
    const int hi = half ? NT : mid;
    const u16* Qh = Qa + (size_t)bh * 2048 * 128;
    const u16* Kh = Ka + (size_t)bh * 2048 * 128;
    const u16* VTh = VT + (size_t)bh * 64 * 2048;
    u16* Pb = half ? P1g : P0g;
    float* Lsb = Ls + (size_t)half * 32 * 2048;

    __shared__ u16 Kl[2][64 * 128];
    __shared__ u16 Vl[2][64 * 64];

    const int tid = threadIdx.x, lane = tid & 63, w = tid >> 6;
    const int l15 = lane & 15, lhi = lane >> 4;
    const float SC = 0.125f * LOG2E;

    bf16x8 qfL[4], qfH[4];
    #pragma unroll
    for (int ks = 0; ks < 4; ++ks) {
        bf16x8 a = *(const bf16x8*)(Qh + (size_t)(q0L + w * 16 + l15) * 128 + ks * 32 + lhi * 8);
        bf16x8 b = *(const bf16x8*)(Qh + (size_t)(q0H + w * 16 + l15) * 128 + ks * 32 + lhi * 8);
        bf16x8 oa, ob;
        #pragma unroll
        for (int j = 0; j < 8; ++j) {
            oa[j] = (short)f2b(b2f((u16)a[j]) * SC);
            ob[j] = (short)f2b(b2f((u16)b[j]) * SC);
        }
        qfL[ks] = oa; qfH[ks] = ob;
    }

    f32x4 accL[4] = {}, accH[4] = {};
    float lsL = 0.f, lsH = 0.f;

    auto STAGE = [&](int buf, int ti) {
        const int kv0 = ti * 64;
        #pragma unroll
        for (int i = 0; i < 4; ++i) {
            int lr = i * 16 + w * 4 + lhi;
            int c = l15 ^ (lr & 15);
            gll16(Kh + (size_t)(kv0 + lr) * 128 + c * 8, &Kl[buf][(i * 16 + w * 4) * 128]);
        }
        #pragma unroll
        for (int i = 0; i < 2; ++i) {
            int dr = i * 32 + w * 8 + (lane >> 3);
            int c = (lane & 7) ^ (dr & 7);
            gll16(VTh + (size_t)dr * 2048 + kv0 + c * 8, &Vl[buf][(i * 32 + w * 8) * 64]);
        }
    };

    STAGE(lo & 1, lo);
    asm volatile("s_waitcnt vmcnt(0)" ::: "memory");
    __builtin_amdgcn_s_barrier();

    for (int ti = lo; ti < hi; ++ti) {
        const int cur = ti & 1;
        if (ti + 1 < hi) STAGE(cur ^ 1, ti + 1);
        const bool doL = (ti <= tiL);

        f32x4 sH[4] = {}, sL[4] = {};
        #pragma unroll
        for (int ks = 0; ks < 4; ++ks) {
            bf16x8 kf[4];
            #pragma unroll
            for (int k2 = 0; k2 < 4; ++k2) {
                int kl = k2 * 16 + l15;
                int cc = (ks * 4 + lhi) ^ l15;
                kf[k2] = *(const bf16x8*)(&Kl[cur][kl * 128 + cc * 8]);
            }
            __builtin_amdgcn_s_setprio(1);
            #pragma unroll
            for (int k2 = 0; k2 < 4; ++k2)
                sH[k2] = __builtin_amdgcn_mfma_f32_16x16x32_bf16(kf[k2], qfH[ks], sH[k2], 0, 0, 0);
            if (doL) {
                #pragma unroll
                for (int k2 = 0; k2 < 4; ++k2)
                    sL[k2] = __builtin_amdgcn_mfma_f32_16x16x32_bf16(kf[k2], qfL[ks], sL[k2], 0, 0, 0);
            }
            __builtin_amdgcn_s_setprio(0);
        }

        auto FINISH = [&](f32x4* sacc, f32x4* acc, float& lsum, bool diag) {
            float p[4][4];
            #pragma unroll
            for (int k2 = 0; k2 < 4; ++k2)
                #pragma unroll
                for (int r = 0; r < 4; ++r) {
                    float s = sacc[k2][r];
                    if (diag) {
                        int key = k2 * 16 + lhi * 4 + r;
                        int qq = w * 16 + l15;
                        s = (key <= qq) ? s : -1e30f;
                    }
                    float pe = fexp2(s);
                    p[k2][r] = pe;
                    lsum += pe;
                }
            bf16x8 pf[2];
            #pragma unroll
            for (int ks2 = 0; ks2 < 2; ++ks2) {
                unsigned int w0, w1, w2, w3;
                asm("v_cvt_pk_bf16_f32 %0, %1, %2" : "=v"(w0) : "v"(p[2 * ks2][0]),     "v"(p[2 * ks2][1]));
                asm("v_cvt_pk_bf16_f32 %0, %1, %2" : "=v"(w1) : "v"(p[2 * ks2][2]),     "v"(p[2 * ks2][3]));
                asm("v_cvt_pk_bf16_f32 %0, %1, %2" : "=v"(w2) : "v"(p[2 * ks2 + 1][0]), "v"(p[2 * ks2 + 1][1]));
                asm("v_cvt_pk_bf16_f32 %0, %1, %2" : "=v"(w3) : "v"(p[2 * ks2 + 1][2]), "v"(p[2 * ks2 + 1][3]));
                u32x4 t = {w0, w1, w2, w3};
                pf[ks2] = __builtin_bit_cast(bf16x8, t);
            }
            #pragma unroll
            for (int ks2 = 0; ks2 < 2; ++ks2) {
                __builtin_amdgcn_s_setprio(1);
                #pragma unroll
                for (int dt = 0; dt < 4; ++dt) {
                    int dd = dt * 16 + l15;
                    int cc = (ks2 * 4 + lhi) ^ (dd & 7);
                    bf16x8 vf = *(const bf16x8*)(&Vl[cur][dd * 64 + cc * 8]);
                    acc[dt] = __builtin_amdgcn_mfma_f32_16x16x32_bf16(pf[ks2], vf, acc[dt], 0, 0, 0);
                }
                __builtin_amdgcn_s_setprio(0);
            }
        };

        FINISH(sH, accH, lsH, ti == tiH);
        if (doL) FINISH(sL, accL, lsL, ti == tiL);

        asm volatile("s_waitcnt vmcnt(0)" ::: "memory");
        __builtin_amdgcn_s_barrier();
    }

    // reduce ls across lhi groups -> full row sums (keyed by l15)
    lsH += __shfl_xor(lsH, 16, 64); lsH += __shfl_xor(lsH, 32, 64);
    lsL += __shfl_xor(lsL, 16, 64); lsL += __shfl_xor(lsL, 32, 64);
    if (lhi == 0) {
        Lsb[(size_t)bh * 2048 + q0H + w * 16 + l15] = lsH;
        Lsb[(size_t)bh * 2048 + q0L + w * 16 + l15] = lsL;
    }

    // store UNNORMALIZED partial O (bf16)
    #pragma unroll
    for (int dt = 0; dt < 4; ++dt)
        #pragma unroll
        for (int r = 0; r < 4; ++r) {
            int cr = lhi * 4 + r;
            int dd = dt * 16 + l15;
            int qgL = q0L + w * 16 + cr;
            int qgH = q0H + w * 16 + cr;
            size_t nL = (size_t)(bh >> 4) * 2048 + qgL;
            size_t nH = (size_t)(bh >> 4) * 2048 + qgH;
            Pb[nL * 1024 + (bh & 15) * 64 + dd] = f2b(accL[dt][r]);
            Pb[nH * 1024 + (bh & 15) * 64 + dd] = f2b(accH[dt][r]);
        }
}

// ---------------- combine: Obuf = (P0 + P1) / (ls0 + ls1) ----------------
__global__ __launch_bounds__(256) void combine_sk(const u16* __restrict__ P0g, const u16* __restrict__ P1g,
                                                  const float* __restrict__ Ls, u16* __restrict__ Obuf) {
    int idx = blockIdx.x * 256 + threadIdx.x;      // 524288 chunks of 8
    size_t base = (size_t)idx * 8;
    int n = (int)(base >> 10);                     // 0..4095
    int col = (int)(base & 1023);
    int b = n >> 11, q = n & 2047, h = col >> 6;
    size_t bhq = (size_t)(b * 16 + h) * 2048 + q;
    float l = Ls[bhq] + Ls[bhq + 32 * 2048];
    float inv = 1.0f / l;
    bf16x8 a = *(const bf16x8*)(P0g + base);
    bf16x8 bb = *(const bf16x8*)(P1g + base);
    bf16x8 o;
    #pragma unroll
    for (int j = 0; j < 8; ++j)
        o[j] = (short)f2b((b2f((u16)a[j]) + b2f((u16)bb[j])) * inv);
    *(bf16x8*)(Obuf + base) = o;
}

// ---------------- launch ----------------
extern "C" void kernel_launch(void* const* d_in, const int* in_sizes, int n_in,
                              void* d_out, int out_size, void* d_ws, size_t ws_size,
                              hipStream_t stream) {
    (void)in_sizes; (void)n_in; (void)out_size; (void)ws_size;
    const float* x  = (const float*)d_in[0];
    const float* Wq = (const float*)d_in[1];
    const float* bq = (const float*)d_in[2];
    const float* Wk = (const float*)d_in[3];
    const float* bk = (const float*)d_in[4];
    const float* Wv = (const float*)d_in[5];
    const float* bv = (const float*)d_in[6];
    const float* Wt = (const float*)d_in[7];
    const float* bt = (const float*)d_in[8];
    const float* Wo = (const float*)d_in[9];
    const float* bo = (const float*)d_in[10];

    const size_t M1 = 1024u * 1024u;
    u16* xb   = (u16*)d_ws;               // 4M (dead after gemm_proj -> reused as VT)
    u16* wq   = xb + 4 * M1;              // dead after gemm_proj -> reused as Ls (f32, 512KB)
    u16* wk   = wq + M1;
    u16* wv   = wk + M1;
    u16* wt   = wv + M1;
    u16* wo   = wt + M1;                  // live until gemm_out2
    u16* Qa   = wo + M1;                  // 8M
    u16* Kaa  = Qa + 8 * M1;              // 8M
    u16* Vtm  = Kaa + 8 * M1;             // 4M (dead after fuse_small -> P0 partial)
    u16* Ttm  = Vtm + 4 * M1;             // 4M (dead after fuse_small -> P1 partial)
    u16* Obuf = Ttm + 4 * M1;             // 4M
    u16* VTg  = xb;
    u16* P0g  = Vtm;
    u16* P1g  = Ttm;
    float* Ls = (float*)wq;

    cvt_all<<<9216, 256, 0, stream>>>(x, Wq, Wk, Wv, Wt, Wo, xb);

    ProjArgs pa;
    pa.W[0] = wq; pa.W[1] = wk; pa.W[2] = wv; pa.W[3] = wt;
    pa.b[0] = bq; pa.b[1] = bk; pa.b[2] = bv; pa.b[3] = bt;
    pa.out[0] = Qa; pa.out[1] = Kaa; pa.out[2] = Vtm; pa.out[3] = Ttm;
    gemm_proj<<<dim3(8, 32, 4), 256, 0, stream>>>(xb, pa);

    fuse_small<<<3200, 256, 0, stream>>>(Qa, Ttm, Vtm, VTg, Kaa);

    attnSK<<<1024, 256, 0, stream>>>(Qa, Kaa, VTg, P0g, P1g, Ls);
    combine_sk<<<2048, 256, 0, stream>>>(P0g, P1g, Ls, Obuf);

    gemm_out2<<<dim3(8, 64), 256, 0, stream>>>(Obuf, wo, bo, d_out);
}

// Round 16
// 138.169 us; speedup vs baseline: 1.0313x; 1.0313x over previous
//
#include <hip/hip_runtime.h>
#include <hip/hip_bf16.h>

typedef unsigned short u16;
typedef __attribute__((ext_vector_type(8))) short bf16x8;
typedef __attribute__((ext_vector_type(4))) float f32x4;
typedef __attribute__((ext_vector_type(4))) unsigned int u32x4;

#define LOG2E 1.44269504088896340736f

static __device__ __forceinline__ float b2f(u16 u) {
    union { float f; unsigned int i; } v; v.i = ((unsigned int)u) << 16; return v.f;
}
static __device__ __forceinline__ u16 f2b(float f) {
    unsigned int x = __builtin_bit_cast(unsigned int, f);
    unsigned int r = (x + 0x7fffu + ((x >> 16) & 1u)) >> 16;
    return (u16)r;
}
static __device__ __forceinline__ void gll16(const u16* g, u16* l) {
    __builtin_amdgcn_global_load_lds((const __attribute__((address_space(1))) void*)g,
                                     (__attribute__((address_space(3))) void*)l, 16, 0, 0);
}
static __device__ __forceinline__ float fexp2(float x) {
    float r; asm("v_exp_f32 %0, %1" : "=v"(r) : "v"(x)); return r;
}

// ---------------- fused fp32 -> bf16 convert ----------------
__global__ __launch_bounds__(256) void cvt_all(const float* __restrict__ x,
                                               const float* __restrict__ w0, const float* __restrict__ w1,
                                               const float* __restrict__ w2, const float* __restrict__ w3,
                                               const float* __restrict__ w4, u16* __restrict__ dst) {
    size_t c = (size_t)blockIdx.x * 256 + threadIdx.x;
    size_t e = c * 4;
    const float* s; size_t off;
    const size_t M4 = (size_t)4 << 20, M1 = (size_t)1 << 20;
    if (e < M4) { s = x; off = e; }
    else {
        size_t r = e - M4; int wsel = (int)(r >> 20); off = r & (M1 - 1);
        s = wsel == 0 ? w0 : wsel == 1 ? w1 : wsel == 2 ? w2 : wsel == 3 ? w3 : w4;
    }
    float4 v = *(const float4*)(s + off);
    u16* d = dst + e;
    d[0] = f2b(v.x); d[1] = f2b(v.y); d[2] = f2b(v.z); d[3] = f2b(v.w);
}

// ---------------- GEMM body (R9 known-good structure), tm/tn passed in ----------------
template<int WM>
static __device__ __forceinline__ void gemm_body(const u16* __restrict__ A, const u16* __restrict__ W,
                                                 const float* __restrict__ bias, void* __restrict__ outp,
                                                 int mode, u16* Al, u16* Bl, int tm, int tn) {
    const int tid = threadIdx.x, lane = tid & 63, w = tid >> 6;
    const int wr = w >> 1, wc = w & 1;
    const int l15 = lane & 15, lhi = lane >> 4;

    f32x4 acc[WM][4] = {};

    for (int kt = 0; kt < 16; ++kt) {
        const int k0 = kt * 64;
        #pragma unroll
        for (int i = 0; i < WM; ++i) {
            int rl = i * 32 + w * 8 + (lane >> 3);
            int c  = (lane & 7) ^ (rl & 7);
            gll16(A + (size_t)(tm + rl) * 1024 + k0 + c * 8, Al + (i * 32 + w * 8) * 64);
        }
        #pragma unroll
        for (int i = 0; i < 4; ++i) {
            int rl = i * 32 + w * 8 + (lane >> 3);
            int c  = (lane & 7) ^ (rl & 7);
            gll16(W + (size_t)(tn + rl) * 1024 + k0 + c * 8, Bl + (i * 32 + w * 8) * 64);
        }
        __syncthreads();
        #pragma unroll
        for (int ks = 0; ks < 2; ++ks) {
            bf16x8 af[WM], bfr[4];
            #pragma unroll
            for (int mi = 0; mi < WM; ++mi) {
                int row = wr * (WM * 16) + mi * 16 + l15;
                int cc = (ks * 4 + lhi) ^ (row & 7);
                af[mi] = *(const bf16x8*)(Al + row * 64 + cc * 8);
            }
            #pragma unroll
            for (int ni = 0; ni < 4; ++ni) {
                int row = wc * 64 + ni * 16 + l15;
                int cc = (ks * 4 + lhi) ^ (row & 7);
                bfr[ni] = *(const bf16x8*)(Bl + row * 64 + cc * 8);
            }
            #pragma unroll
            for (int mi = 0; mi < WM; ++mi)
                #pragma unroll
                for (int ni = 0; ni < 4; ++ni)
                    acc[mi][ni] = __builtin_amdgcn_mfma_f32_16x16x32_bf16(af[mi], bfr[ni], acc[mi][ni], 0, 0, 0);
        }
        __syncthreads();
    }

    float bcol[4];
    #pragma unroll
    for (int ni = 0; ni < 4; ++ni) bcol[ni] = bias[tn + wc * 64 + ni * 16 + l15];

    #pragma unroll
    for (int mi = 0; mi < WM; ++mi)
        #pragma unroll
        for (int ni = 0; ni < 4; ++ni)
            #pragma unroll
            for (int r = 0; r < 4; ++r) {
                int rg = tm + wr * (WM * 16) + mi * 16 + lhi * 4 + r;
                int cg = tn + wc * 64 + ni * 16 + l15;
                float v = acc[mi][ni][r] + bcol[ni];
                if (mode == 2) {
                    ((float*)outp)[(size_t)rg * 1024 + cg] = v;
                } else {
                    int b = rg >> 11, t = rg & 2047, h = cg >> 6, d = cg & 63;
                    if (mode == 0)
                        ((u16*)outp)[(((size_t)(b * 16 + h)) * 2048 + t) * 128 + d] = f2b(v);
                    else
                        ((u16*)outp)[(((size_t)(b * 16 + h)) * 2048 + t) * 64 + d] = f2b(v);
                }
            }
}

struct ProjArgs {
    const u16* W[4];
    const float* b[4];
    u16* out[4];
};

// ---------------- projection GEMM + XCD-chunked dispatch remap (R11, verified) ----------------
__global__ __launch_bounds__(256) void gemm_proj(const u16* __restrict__ A, ProjArgs pa) {
    __shared__ u16 Al[128 * 64];
    __shared__ u16 Bl[128 * 64];
    const int d = blockIdx.x + 8 * blockIdx.y + 256 * blockIdx.z;
    const int c = d & 7, wtn = d >> 3;
    const int z = c >> 1, yh = c & 1;
    const int yy = yh * 16 + (wtn >> 3);
    const int xx = wtn & 7;
    gemm_body<4>(A, pa.W[z], pa.b[z], pa.out[z], (z < 2) ? 0 : 1, Al, Bl, yy * 128, xx * 128);
}

__global__ __launch_bounds__(256) void gemm_out2(const u16* __restrict__ A, const u16* __restrict__ W,
                                                 const float* __restrict__ bias, void* __restrict__ out) {
    __shared__ u16 Al[64 * 64];
    __shared__ u16 Bl[128 * 64];
    const int d = blockIdx.x + 8 * blockIdx.y;
    const int c = d & 7, wtn = d >> 3;
    const int yy = c * 8 + (wtn >> 3);
    const int xx = wtn & 7;
    gemm_body<2>(A, W, bias, out, 2, Al, Bl, yy * 64, xx * 128);
}

// ---------------- fused small kernels (R9, verified) ----------------
__global__ __launch_bounds__(256) void fuse_small(u16* __restrict__ Qa, const u16* __restrict__ Tp,
                                                  const u16* __restrict__ V, u16* __restrict__ VT,
                                                  u16* __restrict__ Ka) {
    __shared__ char shmem[64 * 72 * 2];
    const int b = blockIdx.x, tid = threadIdx.x;

    if (b < 2048) {
        int idx = b * 256 + tid;
        int tg = idx >> 3, dc = idx & 7;
        bf16x8 q = *(const bf16x8*)(Qa + (size_t)tg * 128 + dc * 8);
        bf16x8 tt = *(const bf16x8*)(Tp + (size_t)tg * 64 + dc * 8);
        bf16x8 o;
        #pragma unroll
        for (int j = 0; j < 8; ++j) o[j] = (short)f2b(b2f((u16)q[j]) * b2f((u16)tt[j]));
        *(bf16x8*)(Qa + (size_t)tg * 128 + 64 + dc * 8) = o;
    } else if (b < 3072) {
        u16 (*tile)[72] = (u16(*)[72])shmem;
        const int r0 = b - 2048;
        const int bh = r0 >> 5, tc = r0 & 31;
        const u16* Vh = V + ((size_t)bh * 2048 + tc * 64) * 64;
        u16* VTh = VT + (size_t)bh * 64 * 2048 + tc * 64;
        for (int i = 0; i < 2; ++i) {
            int f = i * 256 + tid;
            int r = f >> 3, dc = f & 7;
            bf16x8 v = *(const bf16x8*)(Vh + r * 64 + dc * 8);
            #pragma unroll
            for (int j = 0; j < 8; ++j) tile[dc * 8 + j][r] = (u16)v[j];
        }
        __syncthreads();
        for (int i = 0; i < 2; ++i) {
            int f = i * 256 + tid;
            int d = f >> 3, t8 = (f & 7) * 8;
            bf16x8 o;
            #pragma unroll
            for (int j = 0; j < 8; ++j) {
                int pos = t8 + j;
                int key = (pos & 32) + 16 * ((pos >> 2) & 1) + 4 * ((pos >> 3) & 3) + (pos & 3);
                o[j] = (short)tile[d][key];
            }
            *(bf16x8*)(VTh + (size_t)d * 2048 + t8) = o;
        }
    } else {
        float4* sums = (float4*)shmem;
        const int r0 = b - 3072;
        const int bh = r0 & 31, dg = r0 >> 5;
        u16* Kh = Ka + (size_t)bh * 2048 * 128;
        const u16* Vh = V + (size_t)bh * 2048 * 64;
        const int quad = tid & 3, c = tid >> 2;
        const int d0 = dg * 16 + quad * 4;
        float s0 = 0.f, s1 = 0.f, s2 = 0.f, s3 = 0.f;
        for (int i = 0; i < 32; ++i) {
            int t = c * 32 + i;
            ushort4 kv = *(const ushort4*)(Kh + (size_t)t * 128 + d0);
            ushort4 vv = *(const ushort4*)(Vh + (size_t)t * 64 + d0);
            s0 += b2f(kv.x) * b2f(vv.x);
            s1 += b2f(kv.y) * b2f(vv.y);
            s2 += b2f(kv.z) * b2f(vv.z);
            s3 += b2f(kv.w) * b2f(vv.w);
        }
        float4 sv; sv.x = s0; sv.y = s1; sv.z = s2; sv.w = s3;
        sums[c * 4 + quad] = sv;
        __syncthreads();
        float4 run; run.x = run.y = run.z = run.w = 0.f;
        for (int cc = 0; cc < c; ++cc) {
            float4 ss = sums[cc * 4 + quad];
            run.x += ss.x; run.y += ss.y; run.z += ss.z; run.w += ss.w;
        }
        for (int i = 0; i < 32; ++i) {
            int t = c * 32 + i;
            ushort4 kv = *(const ushort4*)(Kh + (size_t)t * 128 + d0);
            ushort4 vv = *(const ushort4*)(Vh + (size_t)t * 64 + d0);
            run.x += b2f(kv.x) * b2f(vv.x);
            run.y += b2f(kv.y) * b2f(vv.y);
            run.z += b2f(kv.z) * b2f(vv.z);
            run.w += b2f(kv.w) * b2f(vv.w);
            ushort4 o;
            o.x = f2b(run.x * 0.125f); o.y = f2b(run.y * 0.125f);
            o.z = f2b(run.z * 0.125f); o.w = f2b(run.w * 0.125f);
            *(ushort4*)(Kh + (size_t)t * 128 + 64 + d0) = o;
        }
    }
}

// ---------------- flash attention (verified 51.3us): 48KB ring-2, register P, mirror-paired ----------------
__global__ __launch_bounds__(256, 3) void attn5(const u16* __restrict__ Qa, const u16* __restrict__ Ka,
                                                const u16* __restrict__ VT, u16* __restrict__ Obuf) {
    const int wg = blockIdx.x;
    const int xcd = wg & 7, slot = wg >> 3;
    const int bh = xcd * 4 + (slot >> 4);
    const int qp = slot & 15;
    const int tiL = qp, tiH = 31 - qp;
    const int q0L = tiL * 64, q0H = tiH * 64;
    const int NT = tiH + 1;
    const u16* Qh = Qa + (size_t)bh * 2048 * 128;
    const u16* Kh = Ka + (size_t)bh * 2048 * 128;
    const u16* VTh = VT + (size_t)bh * 64 * 2048;

    __shared__ u16 Kl[2][64 * 128];
    __shared__ u16 Vl[2][64 * 64];

    const int tid = threadIdx.x, lane = tid & 63, w = tid >> 6;
    const int l15 = lane & 15, lhi = lane >> 4;
    const float SC = 0.125f * LOG2E;

    bf16x8 qfL[4], qfH[4];
    #pragma unroll
    for (int ks = 0; ks < 4; ++ks) {
        bf16x8 a = *(const bf16x8*)(Qh + (size_t)(q0L + w * 16 + l15) * 128 + ks * 32 + lhi * 8);
        bf16x8 b = *(const bf16x8*)(Qh + (size_t)(q0H + w * 16 + l15) * 128 + ks * 32 + lhi * 8);
        bf16x8 oa, ob;
        #pragma unroll
        for (int j = 0; j < 8; ++j) {
            oa[j] = (short)f2b(b2f((u16)a[j]) * SC);
            ob[j] = (short)f2b(b2f((u16)b[j]) * SC);
        }
        qfL[ks] = oa; qfH[ks] = ob;
    }

    f32x4 accL[4] = {}, accH[4] = {};
    float lsL = 0.f, lsH = 0.f;

    auto STAGE = [&](int buf, int ti) {
        const int kv0 = ti * 64;
        #pragma unroll
        for (int i = 0; i < 4; ++i) {
            int lr = i * 16 + w * 4 + lhi;
            int c = l15 ^ (lr & 15);
            gll16(Kh + (size_t)(kv0 + lr) * 128 + c * 8, &Kl[buf][(i * 16 + w * 4) * 128]);
        }
        #pragma unroll
        for (int i = 0; i < 2; ++i) {
            int dr = i * 32 + w * 8 + (lane >> 3);
            int c = (lane & 7) ^ (dr & 7);
            gll16(VTh + (size_t)dr * 2048 + kv0 + c * 8, &Vl[buf][(i * 32 + w * 8) * 64]);
        }
    };

    STAGE(0, 0);
    asm volatile("s_waitcnt vmcnt(0)" ::: "memory");
    __builtin_amdgcn_s_barrier();

    for (int ti = 0; ti < NT; ++ti) {
        const int cur = ti & 1;
        if (ti + 1 < NT) STAGE(cur ^ 1, ti + 1);
        const bool doL = (ti <= tiL);

        f32x4 sH[4] = {}, sL[4] = {};
        #pragma unroll
        for (int ks = 0; ks < 4; ++ks) {
            bf16x8 kf[4];
            #pragma unroll
            for (int k2 = 0; k2 < 4; ++k2) {
                int kl = k2 * 16 + l15;
                int cc = (ks * 4 + lhi) ^ l15;
                kf[k2] = *(const bf16x8*)(&Kl[cur][kl * 128 + cc * 8]);
            }
            __builtin_amdgcn_s_setprio(1);
            #pragma unroll
            for (int k2 = 0; k2 < 4; ++k2)
                sH[k2] = __builtin_amdgcn_mfma_f32_16x16x32_bf16(kf[k2], qfH[ks], sH[k2], 0, 0, 0);
            if (doL) {
                #pragma unroll
                for (int k2 = 0; k2 < 4; ++k2)
                    sL[k2] = __builtin_amdgcn_mfma_f32_16x16x32_bf16(kf[k2], qfL[ks], sL[k2], 0, 0, 0);
            }
            __builtin_amdgcn_s_setprio(0);
        }

        auto FINISH = [&](f32x4* sacc, f32x4* acc, float& lsum, bool diag) {
            float p[4][4];
            #pragma unroll
            for (int k2 = 0; k2 < 4; ++k2)
                #pragma unroll
                for (int r = 0; r < 4; ++r) {
                    float s = sacc[k2][r];
                    if (diag) {
                        int key = k2 * 16 + lhi * 4 + r;
                        int qq = w * 16 + l15;
                        s = (key <= qq) ? s : -1e30f;
                    }
                    float pe = fexp2(s);
                    p[k2][r] = pe;
                    lsum += pe;
                }
            bf16x8 pf[2];
            #pragma unroll
            for (int ks2 = 0; ks2 < 2; ++ks2) {
                unsigned int w0, w1, w2, w3;
                asm("v_cvt_pk_bf16_f32 %0, %1, %2" : "=v"(w0) : "v"(p[2 * ks2][0]),     "v"(p[2 * ks2][1]));
                asm("v_cvt_pk_bf16_f32 %0, %1, %2" : "=v"(w1) : "v"(p[2 * ks2][2]),     "v"(p[2 * ks2][3]));
                asm("v_cvt_pk_bf16_f32 %0, %1, %2" : "=v"(w2) : "v"(p[2 * ks2 + 1][0]), "v"(p[2 * ks2 + 1][1]));
                asm("v_cvt_pk_bf16_f32 %0, %1, %2" : "=v"(w3) : "v"(p[2 * ks2 + 1][2]), "v"(p[2 * ks2 + 1][3]));
                u32x4 t = {w0, w1, w2, w3};
                pf[ks2] = __builtin_bit_cast(bf16x8, t);
            }
            #pragma unroll
            for (int ks2 = 0; ks2 < 2; ++ks2) {
                __builtin_amdgcn_s_setprio(1);
                #pragma unroll
                for (int dt = 0; dt < 4; ++dt) {
                    int dd = dt * 16 + l15;
                    int cc = (ks2 * 4 + lhi) ^ (dd & 7);
                    bf16x8 vf = *(const bf16x8*)(&Vl[cur][dd * 64 + cc * 8]);
                    acc[dt] = __builtin_amdgcn_mfma_f32_16x16x32_bf16(pf[ks2], vf, acc[dt], 0, 0, 0);
                }
                __builtin_amdgcn_s_setprio(0);
            }
        };

        FINISH(sH, accH, lsH, ti == tiH);
        if (doL) FINISH(sL, accL, lsL, ti == tiL);

        asm volatile("s_waitcnt vmcnt(0)" ::: "memory");
        __builtin_amdgcn_s_barrier();
    }

    lsH += __shfl_xor(lsH, 16, 64); lsH += __shfl_xor(lsH, 32, 64);
    lsL += __shfl_xor(lsL, 16, 64); lsL += __shfl_xor(lsL, 32, 64);
    float invH[4], invL[4];
    #pragma unroll
    for (int r = 0; r < 4; ++r) {
        invH[r] = 1.0f / __shfl(lsH, lhi * 4 + r, 64);
        invL[r] = 1.0f / __shfl(lsL, lhi * 4 + r, 64);
    }
    #pragma unroll
    for (int dt = 0; dt < 4; ++dt)
        #pragma unroll
        for (int r = 0; r < 4; ++r) {
            int cr = lhi * 4 + r;
            int dd = dt * 16 + l15;
            int qgL = q0L + w * 16 + cr;
            int qgH = q0H + w * 16 + cr;
            size_t nL = (size_t)(bh >> 4) * 2048 + qgL;
            size_t nH = (size_t)(bh >> 4) * 2048 + qgH;
            Obuf[nL * 1024 + (bh & 15) * 64 + dd] = f2b(accL[dt][r] * invL[r]);
            Obuf[nH * 1024 + (bh & 15) * 64 + dd] = f2b(accH[dt][r] * invH[r]);
        }
}

// ---------------- launch ----------------
extern "C" void kernel_launch(void* const* d_in, const int* in_sizes, int n_in,
                              void* d_out, int out_size, void* d_ws, size_t ws_size,
                              hipStream_t stream) {
    (void)in_sizes; (void)n_in; (void)out_size; (void)ws_size;
    const float* x  = (const float*)d_in[0];
    const float* Wq = (const float*)d_in[1];
    const float* bq = (const float*)d_in[2];
    const float* Wk = (const float*)d_in[3];
    const float* bk = (const float*)d_in[4];
    const float* Wv = (const float*)d_in[5];
    const float* bv = (const float*)d_in[6];
    const float* Wt = (const float*)d_in[7];
    const float* bt = (const float*)d_in[8];
    const float* Wo = (const float*)d_in[9];
    const float* bo = (const float*)d_in[10];

    const size_t M1 = 1024u * 1024u;
    u16* xb   = (u16*)d_ws;               // 4M (dead after gemm_proj -> reused as VT)
    u16* wq   = xb + 4 * M1;
    u16* wk   = wq + M1;
    u16* wv   = wk + M1;
    u16* wt   = wv + M1;
    u16* wo   = wt + M1;
    u16* Qa   = wo + M1;                  // 8M
    u16* Kaa  = Qa + 8 * M1;              // 8M
    u16* Vtm  = Kaa + 8 * M1;             // 4M
    u16* Ttm  = Vtm + 4 * M1;             // 4M
    u16* Obuf = Ttm + 4 * M1;             // 4M
    u16* VTg  = xb;

    cvt_all<<<9216, 256, 0, stream>>>(x, Wq, Wk, Wv, Wt, Wo, xb);

    ProjArgs pa;
    pa.W[0] = wq; pa.W[1] = wk; pa.W[2] = wv; pa.W[3] = wt;
    pa.b[0] = bq; pa.b[1] = bk; pa.b[2] = bv; pa.b[3] = bt;
    pa.out[0] = Qa; pa.out[1] = Kaa; pa.out[2] = Vtm; pa.out[3] = Ttm;
    gemm_proj<<<dim3(8, 32, 4), 256, 0, stream>>>(xb, pa);

    fuse_small<<<3200, 256, 0, stream>>>(Qa, Ttm, Vtm, VTg, Kaa);

    attn5<<<512, 256, 0, stream>>>(Qa, Kaa, VTg, Obuf);

    gemm_out2<<<dim3(8, 64), 256, 0, stream>>>(Obuf, wo, bo, d_out);
}